// Round 14
// baseline (125.413 us; speedup 1.0000x reference)
//
#include <hip/hip_runtime.h>
#include <cstdint>

#define IN_DIM   128
#define OUT_DIM  256
#define NROWS    32768
#define NSTEPS   32            // K = 4096 = 32 * 128 (4 i-values per kt)

typedef unsigned short u16;
typedef __attribute__((ext_vector_type(8)))  __bf16 bf16x8;
typedef __attribute__((ext_vector_type(16))) float  f32x16;
typedef __attribute__((ext_vector_type(4)))  float  f32x4v;

// ---------------------------------------------------------------------------
// Prep: repack fouriercoeffs (2,256,128,16) f32 -> Bpack bf16 [K/8][256][8]
// with k = i*32 + t*16 + g  (t: 0=cos, 1=sin; slot g holds harmonic g+1).
// ---------------------------------------------------------------------------
__global__ __launch_bounds__(256) void kan_prep(const float* __restrict__ C,
                                                u16* __restrict__ Bpack) {
    const int o = threadIdx.x;   // 0..255 output channel
    const int i = blockIdx.x;    // 0..127 input dim
    const int t = blockIdx.y;    // 0=cos, 1=sin
    const float* src = C + (((size_t)(t * OUT_DIM + o) * IN_DIM + i) * 16);
    bf16x8 lo = {}, hi = {};
#pragma unroll
    for (int g = 0; g < 8; ++g) {
        lo[g] = (__bf16)src[g];
        hi[g] = (__bf16)src[8 + g];
    }
    const int ko = i * 4 + t * 2;       // k>>3
    bf16x8* dst = (bf16x8*)Bpack;
    dst[(size_t)ko * OUT_DIM + o]       = lo;   // g = 0..7
    dst[(size_t)(ko + 1) * OUT_DIM + o] = hi;   // g = 8..15
}

// cross-half exchange: lane l <-> lane l^32, 4 dwords of a bf16x8
__device__ inline bf16x8 swap32(bf16x8 v) {
    union { bf16x8 h; int i[4]; } u;
    u.h = v;
#pragma unroll
    for (int j = 0; j < 4; ++j) u.i[j] = __shfl_xor(u.i[j], 32, 64);
    return u.h;
}

// ---------------------------------------------------------------------------
// Fused trig + bf16 MFMA GEMM, v14 = v12 reshaped for 2 waves/SIMD w/o spill.
//  - Wave tile 64x64 (fm2 x fn2 of 32x32x16): acc 64 regs (v13's 128-reg acc
//    + 256 cap = measured spill). B/FLOP still 1/64; total B traffic
//    unchanged (2048 blocks x 0.5 MB = 1.07 GB, L2-resident).
//  - Grid 2048 one-wave blocks = 2 waves/SIMD, NO LDS buffers, NO barriers,
//    no merge (disjoint outputs). v12's scheduler freedom at 2x occupancy.
//  - shfl-exchange trig (T12 mechanism): each lane computes ONE full
//    16-harmonic chain for row la31+32*gh, then ONE shfl_xor(32) round
//    exchanges the unused half with the partner lane -> both fm-fragments.
//    Chain work per lane HALVES vs v12 (R=4 -> R=2 effective).
//      lane gh=0: keeps qc0 (rowA h1-8) as afc0, sends qc1, recv -> afc1
//      lane gh=1: keeps qc1 (rowB h9-16) as afc1, sends qc0, recv -> afc0
//  - launch_bounds(64,2): 256-reg cap, need ~140. No spill possible.
// ---------------------------------------------------------------------------
__global__ __launch_bounds__(64, 2) void kan_gemm(const float* __restrict__ x,
                                                  const u16* __restrict__ Bpack,
                                                  const float* __restrict__ bias,
                                                  float* __restrict__ out) {
    const int lane = threadIdx.x;    // 0..63
    const int la31 = lane & 31;
    const int gh   = lane >> 5;      // 0..1: k-half within each K=16 window
    const int bid  = blockIdx.x;
    const int wn   = bid & 3;        // col group: 64 cols
    const int m0   = (bid >> 2) * 64;

    f32x16 vz;
#pragma unroll
    for (int r = 0; r < 16; ++r) vz[r] = 0.f;
    f32x16 acc[2][2] = {{vz, vz}, {vz, vz}};

    const bf16x8* Bv = (const bf16x8*)Bpack;
    const int bcol = wn * 64 + la31;           // + fn*32 per fragment

    // this lane's ONE row: la31 + 32*gh
    const float* xr = x + (size_t)(m0 + la31 + 32 * gh) * IN_DIM;

    // x double-buffer (4 floats per kt, 16B-aligned)
    f32x4v xa = *(const f32x4v*)(xr);

    for (int kt = 0; kt < NSTEPS; ++kt) {
        const int ktn = (kt + 1) & (NSTEPS - 1);
        const f32x4v xa_n = *(const f32x4v*)(xr + ktn * 4);

#pragma unroll
        for (int i = 0; i < 4; ++i) {
            // B fragments for this i's cos & sin windows.
            // ko = i_glob*4 + t*2 + gh, i_glob = kt*4+i  (matches kan_prep)
            const size_t koc = (size_t)((kt * 4 + i) * 4 + gh);
            bf16x8 bgc[2], bgs[2];
#pragma unroll
            for (int fn = 0; fn < 2; ++fn) {
                bgc[fn] = Bv[koc * OUT_DIM + bcol + fn * 32];
                bgs[fn] = Bv[(koc + 2) * OUT_DIM + bcol + fn * 32];
            }

            // ONE full 16-harmonic Chebyshev chain for this lane's row
            bf16x8 qc0 = {}, qc1 = {}, qs0 = {}, qs1 = {};
            {
                float s1, c1;
                __sincosf(xa[i], &s1, &c1);
                const float t2 = 2.f * c1;
                float cp = c1, sp = s1;                    // harmonic 1
                float cc = t2 * c1 - 1.f, sc = t2 * s1;    // harmonic 2
                qc0[0] = (__bf16)cp;  qs0[0] = (__bf16)sp;
                qc0[1] = (__bf16)cc;  qs0[1] = (__bf16)sc;
#pragma unroll
                for (int g = 3; g <= 16; ++g) {            // 2 FMA each
                    const float cn = t2 * cc - cp;
                    const float sn = t2 * sc - sp;
                    cp = cc; sp = sc; cc = cn; sc = sn;
                    const int idx = g - 1;                 // slot = harmonic-1
                    if (idx < 8) { qc0[idx] = (__bf16)cc;      qs0[idx] = (__bf16)sc; }
                    else         { qc1[idx - 8] = (__bf16)cc;  qs1[idx - 8] = (__bf16)sc; }
                }
            }

            // exchange unused halves with partner lane (l ^ 32)
            const bf16x8 recv_c = swap32(gh ? qc0 : qc1);
            const bf16x8 recv_s = swap32(gh ? qs0 : qs1);
            const bf16x8 afc0 = gh ? recv_c : qc0;   // row la31,    k-half gh
            const bf16x8 afc1 = gh ? qc1 : recv_c;   // row la31+32, k-half gh
            const bf16x8 afs0 = gh ? recv_s : qs0;
            const bf16x8 afs1 = gh ? qs1 : recv_s;

            // cos window (k = i_glob*32 + 0..15)
#pragma unroll
            for (int fn = 0; fn < 2; ++fn) {
                acc[0][fn] = __builtin_amdgcn_mfma_f32_32x32x16_bf16(afc0, bgc[fn], acc[0][fn], 0, 0, 0);
                acc[1][fn] = __builtin_amdgcn_mfma_f32_32x32x16_bf16(afc1, bgc[fn], acc[1][fn], 0, 0, 0);
            }
            // sin window (k = i_glob*32 + 16..31)
#pragma unroll
            for (int fn = 0; fn < 2; ++fn) {
                acc[0][fn] = __builtin_amdgcn_mfma_f32_32x32x16_bf16(afs0, bgs[fn], acc[0][fn], 0, 0, 0);
                acc[1][fn] = __builtin_amdgcn_mfma_f32_32x32x16_bf16(afs1, bgs[fn], acc[1][fn], 0, 0, 0);
            }
        }
        xa = xa_n;
    }

    // ---- epilogue (verified 32x32 C/D layout):
    //      col = lane&31 (+fn*32), row = (r&3) + 8*(r>>2) + 4*gh (+fm*32)
#pragma unroll
    for (int fn = 0; fn < 2; ++fn) {
        const int col = bcol + fn * 32;
        const float bv = bias[col];
#pragma unroll
        for (int fm = 0; fm < 2; ++fm) {
            const int rbase = m0 + fm * 32 + 4 * gh;
#pragma unroll
            for (int r = 0; r < 16; ++r) {
                const int row = rbase + (r & 3) + 8 * (r >> 2);
                out[(size_t)row * OUT_DIM + col] = acc[fm][fn][r] + bv;
            }
        }
    }
}

extern "C" void kernel_launch(void* const* d_in, const int* in_sizes, int n_in,
                              void* d_out, int out_size, void* d_ws, size_t ws_size,
                              hipStream_t stream) {
    const float* x    = (const float*)d_in[0];   // (32768, 128) f32
    const float* fc   = (const float*)d_in[1];   // (2, 256, 128, 16) f32
    const float* bias = (const float*)d_in[2];   // (1, 256) f32
    float* out        = (float*)d_out;           // (32768, 256) f32
    u16* Bpack        = (u16*)d_ws;              // 4096*256*2 B = 2 MB scratch

    kan_prep<<<dim3(IN_DIM, 2), OUT_DIM, 0, stream>>>(fc, Bpack);
    kan_gemm<<<dim3(NROWS / 64 * 4), 64, 0, stream>>>(x, Bpack, bias, out);
}

// Round 15
// 86.290 us; speedup vs baseline: 1.4534x; 1.4534x over previous
//
#include <hip/hip_runtime.h>
#include <cstdint>

#define IN_DIM   128
#define OUT_DIM  256
#define NROWS    32768
#define NSTEPS   32            // K = 4096 = 32 * 128 (4 i-values per kt)
#define STR      65            // bf16x8 row stride (64 + 1 pad)

typedef unsigned short u16;
typedef __attribute__((ext_vector_type(8)))  __bf16 bf16x8;
typedef __attribute__((ext_vector_type(16))) float  f32x16;

// lgkm-only barrier (proven safe v10): drains LDS ops, leaves B loads in
// flight across the barrier.
#define BARRIER_LGKM()                                         \
    do {                                                       \
        asm volatile("s_waitcnt lgkmcnt(0)" ::: "memory");     \
        __builtin_amdgcn_s_barrier();                          \
    } while (0)

// ---------------------------------------------------------------------------
// Prep: repack fouriercoeffs (2,256,128,16) f32 -> Bpack bf16 [K/8][256][8]
// with k = i*32 + t*16 + g  (t: 0=cos, 1=sin; slot g holds harmonic g+1).
// ---------------------------------------------------------------------------
__global__ __launch_bounds__(256) void kan_prep(const float* __restrict__ C,
                                                u16* __restrict__ Bpack) {
    const int o = threadIdx.x;   // 0..255 output channel
    const int i = blockIdx.x;    // 0..127 input dim
    const int t = blockIdx.y;    // 0=cos, 1=sin
    const float* src = C + (((size_t)(t * OUT_DIM + o) * IN_DIM + i) * 16);
    bf16x8 lo = {}, hi = {};
#pragma unroll
    for (int g = 0; g < 8; ++g) {
        lo[g] = (__bf16)src[g];
        hi[g] = (__bf16)src[8 + g];
    }
    const int ko = i * 4 + t * 2;       // k>>3
    bf16x8* dst = (bf16x8*)Bpack;
    dst[(size_t)ko * OUT_DIM + o]       = lo;   // g = 0..7
    dst[(size_t)(ko + 1) * OUT_DIM + o] = hi;   // g = 8..15
}

// ---------------------------------------------------------------------------
// Fused trig + bf16 MFMA GEMM, v15 = v10 with a 2-WAVE BARRIER DOMAIN.
//  - Diagnosis (v7/v10 plateau, MfmaUtil ~40%): barrier-locked waves march
//    in phase lockstep — both SIMD-resident waves gen together (MFMA pipe
//    idle) then MFMA together (VALU idle). m114 co-scheduling needs
//    co-resident waves in DIFFERENT phases.
//  - Fix: block = 2 waves (64 rows x 128 cols), grid 1024. LDS 33.3 KB ->
//    4 independent blocks/CU (133 KB), still 8 waves/CU = 2/SIMD, but the
//    2 waves on a SIMD come from different blocks with independent
//    barriers -> natural de-phasing, gen overlaps partner's MFMA.
//  - Per-block structure v10-verbatim: dbuf A-LDS (STR=65), bA/bB static B
//    sets with cross-barrier flight (lgkm-only barrier), 32x32x16 MFMA
//    fm2 x fn2, 1/64 + 1/64 traffic ledger. Gen: 2 chains/thread (rows tr,
//    tr+32) — trig R=2 (+~2us VALU, paid for de-phasing).
// ---------------------------------------------------------------------------
__global__ __launch_bounds__(128, 2) void kan_gemm(const float* __restrict__ x,
                                                   const u16* __restrict__ Bpack,
                                                   const float* __restrict__ bias,
                                                   float* __restrict__ out) {
    __shared__ __align__(16) u16 Asm[2][16 * STR * 8];   // 2 x 16640 B

    const int tid  = threadIdx.x;
    const int lane = tid & 63;
    const int wid  = tid >> 6;       // 0..1  col half within block (64 cols)
    const int la31 = lane & 31;
    const int gh   = lane >> 5;      // 0..1  k-half within a K=16 window
    const int bid  = blockIdx.x;
    const int wnb  = bid & 1;        // block col half (128 cols)
    const int m0   = (bid >> 1) * 64;

    // trig task mapping: 128 threads x 2 rows = 64 rows x 4 i-subs
    const int tr  = (tid >> 2) & 31; // 0..31 (rows tr and tr+32)
    const int til = tid & 3;         // 0..3, i = kt*4 + til

    f32x16 vz;
#pragma unroll
    for (int r = 0; r < 16; ++r) vz[r] = 0.f;
    f32x16 acc[2][2] = {{vz, vz}, {vz, vz}};

    const bf16x8* Bv = (const bf16x8*)Bpack;
    bf16x8* Av0 = (bf16x8*)Asm[0];
    bf16x8* Av1 = (bf16x8*)Asm[1];

    const int bcol = wnb * 128 + wid * 64 + la31;   // + fn*32 per fragment

    // ---- harmonic generator (v10 numerics): 4 ds_write_b128 per chain ----
    auto gen = [&](bf16x8* Av, float xv, int trL) {
        float s1, c1;
        __sincosf(xv, &s1, &c1);
        const float t2 = 2.f * c1;
        bf16x8 qc0 = {}, qc1 = {}, qs0 = {}, qs1 = {};
        float cp = c1, sp = s1;                    // harmonic 1
        float cc = t2 * c1 - 1.f, sc = t2 * s1;    // harmonic 2
        qc0[0] = (__bf16)cp;  qs0[0] = (__bf16)sp;
        qc0[1] = (__bf16)cc;  qs0[1] = (__bf16)sc;
#pragma unroll
        for (int g = 3; g <= 16; ++g) {            // Chebyshev: 2 FMA each
            const float cn = t2 * cc - cp;
            const float sn = t2 * sc - sp;
            cp = cc; sp = sc; cc = cn; sc = sn;
            const int idx = g - 1;                 // slot = harmonic-1
            if (idx < 8) { qc0[idx] = (__bf16)cc;      qs0[idx] = (__bf16)sc; }
            else         { qc1[idx - 8] = (__bf16)cc;  qs1[idx - 8] = (__bf16)sc; }
        }
        const int kob = til * 4;   // local ko = til*4 + t*2 + (g>>3)
        Av[(kob + 0) * STR + trL] = qc0;
        Av[(kob + 1) * STR + trL] = qc1;
        Av[(kob + 2) * STR + trL] = qs0;
        Av[(kob + 3) * STR + trL] = qs1;
    };

    const float* xr0 = x + (size_t)(m0 + tr) * IN_DIM + til;
    const float* xr1 = xr0 + (size_t)32 * IN_DIM;

    // B fragment pipeline: bA kw0-3, bB kw4-7 (static idx only, no copies)
    bf16x8 bA[8], bB[8];

    // prologue: bA <- kt0 kw0-3; gen tile 0 (both rows); x for tile 1
#pragma unroll
    for (int j = 0; j < 4; ++j)
#pragma unroll
        for (int fn = 0; fn < 2; ++fn)
            bA[j * 2 + fn] = Bv[(size_t)((j >> 1) * 4 + (j & 1) * 2 + gh) * OUT_DIM
                                + bcol + fn * 32];
    float xa = xr0[0], xb = xr1[0];
    float xan = xr0[4], xbn = xr1[4];
    gen(Av0, xa, tr);
    gen(Av0, xb, tr + 32);
    BARRIER_LGKM();

    for (int kt = 0; kt < NSTEPS; ++kt) {
        bf16x8* Avc = (kt & 1) ? Av1 : Av0;
        bf16x8* Avn = (kt & 1) ? Av0 : Av1;

        // issue bB: kw4-7 of THIS kt (used after gen + 16 MFMA)
#pragma unroll
        for (int j = 0; j < 4; ++j)
#pragma unroll
            for (int fn = 0; fn < 2; ++fn)
                bB[j * 2 + fn] = Bv[(size_t)(kt * 16 + 8 + (j >> 1) * 4 + (j & 1) * 2 + gh)
                                    * OUT_DIM + bcol + fn * 32];

        // generate next A tile (2 chains) — fills the bB load shadow
        if (kt + 1 < NSTEPS) {
            gen(Avn, xan, tr);
            gen(Avn, xbn, tr + 32);
            const int k2 = ((kt + 2) & (NSTEPS - 1)) * 4;
            xan = xr0[k2];
            xbn = xr1[k2];
        }

        // MFMA kw0-3 from bA (in flight across the previous barrier)
#pragma unroll
        for (int j = 0; j < 4; ++j) {
            const int koL = (j >> 1) * 4 + (j & 1) * 2 + gh;
            const bf16x8 af0 = Avc[koL * STR + la31];
            const bf16x8 af1 = Avc[koL * STR + 32 + la31];
            acc[0][0] = __builtin_amdgcn_mfma_f32_32x32x16_bf16(af0, bA[j*2+0], acc[0][0], 0, 0, 0);
            acc[0][1] = __builtin_amdgcn_mfma_f32_32x32x16_bf16(af0, bA[j*2+1], acc[0][1], 0, 0, 0);
            acc[1][0] = __builtin_amdgcn_mfma_f32_32x32x16_bf16(af1, bA[j*2+0], acc[1][0], 0, 0, 0);
            acc[1][1] = __builtin_amdgcn_mfma_f32_32x32x16_bf16(af1, bA[j*2+1], acc[1][1], 0, 0, 0);
        }

        // issue bA: kw0-3 of NEXT kt (stays in flight across the barrier)
        {
            const int ktn = (kt + 1) & (NSTEPS - 1);
#pragma unroll
            for (int j = 0; j < 4; ++j)
#pragma unroll
                for (int fn = 0; fn < 2; ++fn)
                    bA[j * 2 + fn] = Bv[(size_t)(ktn * 16 + (j >> 1) * 4 + (j & 1) * 2 + gh)
                                        * OUT_DIM + bcol + fn * 32];
        }

        // MFMA kw4-7 from bB
#pragma unroll
        for (int j = 0; j < 4; ++j) {
            const int koL = 8 + (j >> 1) * 4 + (j & 1) * 2 + gh;
            const bf16x8 af0 = Avc[koL * STR + la31];
            const bf16x8 af1 = Avc[koL * STR + 32 + la31];
            acc[0][0] = __builtin_amdgcn_mfma_f32_32x32x16_bf16(af0, bB[j*2+0], acc[0][0], 0, 0, 0);
            acc[0][1] = __builtin_amdgcn_mfma_f32_32x32x16_bf16(af0, bB[j*2+1], acc[0][1], 0, 0, 0);
            acc[1][0] = __builtin_amdgcn_mfma_f32_32x32x16_bf16(af1, bB[j*2+0], acc[1][0], 0, 0, 0);
            acc[1][1] = __builtin_amdgcn_mfma_f32_32x32x16_bf16(af1, bB[j*2+1], acc[1][1], 0, 0, 0);
        }
        BARRIER_LGKM();
    }

    // ---- epilogue (verified 32x32 C/D layout):
    //      col = lane&31 (+fn*32), row = (r&3) + 8*(r>>2) + 4*gh (+fm*32)
#pragma unroll
    for (int fn = 0; fn < 2; ++fn) {
        const int col = bcol + fn * 32;
        const float bv = bias[col];
#pragma unroll
        for (int fm = 0; fm < 2; ++fm) {
            const int rbase = m0 + fm * 32 + 4 * gh;
#pragma unroll
            for (int r = 0; r < 16; ++r) {
                const int row = rbase + (r & 3) + 8 * (r >> 2);
                out[(size_t)row * OUT_DIM + col] = acc[fm][fn][r] + bv;
            }
        }
    }
}

extern "C" void kernel_launch(void* const* d_in, const int* in_sizes, int n_in,
                              void* d_out, int out_size, void* d_ws, size_t ws_size,
                              hipStream_t stream) {
    const float* x    = (const float*)d_in[0];   // (32768, 128) f32
    const float* fc   = (const float*)d_in[1];   // (2, 256, 128, 16) f32
    const float* bias = (const float*)d_in[2];   // (1, 256) f32
    float* out        = (float*)d_out;           // (32768, 256) f32
    u16* Bpack        = (u16*)d_ws;              // 4096*256*2 B = 2 MB scratch

    kan_prep<<<dim3(IN_DIM, 2), OUT_DIM, 0, stream>>>(fc, Bpack);
    kan_gemm<<<dim3(NROWS / 64 * 2), 128, 0, stream>>>(x, Bpack, bias, out);
}